// Round 4
// baseline (3471.547 us; speedup 1.0000x reference)
//
#include <hip/hip_runtime.h>
#include <math.h>

// NTM: (1) serial h-chain kernel (128 blocks, 3 fence-free grid barriers/step;
// all cross-block data via agent-scope relaxed atomics -> LLC-coherent, no
// buffer_wbl2/buffer_inv), (2) parallel c-scan kernel streaming 268 MB cs.
// Shapes: N=32, T=64, C1=128, C2=256, H=512 (all f32).

#define NBAT 32
#define TSTEPS 64
#define C1D 128
#define C2D 256
#define HD 512
#define NBLK 128  // chain blocks

typedef float f32x4 __attribute__((ext_vector_type(4)));

static __device__ __forceinline__ float dot4f(float4 a, float4 b) {
  return a.x * b.x + a.y * b.y + a.z * b.z + a.w * b.w;
}
static __device__ __forceinline__ float sigm(float x) { return 1.0f / (1.0f + __expf(-x)); }

// ---- agent-scope (device-coherent, L2-bypassing) access helpers ----
static __device__ __forceinline__ float aload(const float* p) {
  return __hip_atomic_load(p, __ATOMIC_RELAXED, __HIP_MEMORY_SCOPE_AGENT);
}
static __device__ __forceinline__ void astore(float* p, float v) {
  __hip_atomic_store(p, v, __ATOMIC_RELAXED, __HIP_MEMORY_SCOPE_AGENT);
}
static __device__ __forceinline__ float2 aload2(const float* p) {
  unsigned long long u = __hip_atomic_load((const unsigned long long*)p,
                                           __ATOMIC_RELAXED, __HIP_MEMORY_SCOPE_AGENT);
  union { unsigned long long u; float2 f; } c;
  c.u = u;
  return c.f;
}
static __device__ __forceinline__ void astore2(float* p, float a, float b) {
  union { float f[2]; unsigned long long u; } c;
  c.f[0] = a; c.f[1] = b;
  __hip_atomic_store((unsigned long long*)p, c.u, __ATOMIC_RELAXED, __HIP_MEMORY_SCOPE_AGENT);
}
static __device__ __forceinline__ float4 aload4(const float* p) {
  const float2 lo = aload2(p), hi = aload2(p + 2);
  return make_float4(lo.x, lo.y, hi.x, hi.y);
}

__global__ void __launch_bounds__(256) ntm_chain(
    const float* __restrict__ h0, const float* __restrict__ c_x,
    const float* __restrict__ Wk, const float* __restrict__ bk,
    const float* __restrict__ Wb, const float* __restrict__ bb,
    const float* __restrict__ We, const float* __restrict__ be,
    const float* __restrict__ Wv, const float* __restrict__ bv,
    const float* __restrict__ Wih, const float* __restrict__ bih,
    const float* __restrict__ Whh, const float* __restrict__ bhh,
    float* __restrict__ hs_out, float* __restrict__ wsf, unsigned* __restrict__ bar)
{
  const int tid = threadIdx.x;
  const int bid = blockIdx.x;
  const int lane = tid & 63;
  const int wid = tid >> 6;

  // ---- workspace layout (floats) ----
  float* hbufA = wsf;                          // [32*512]
  float* hbufB = hbufA + NBAT * HD;            // [32*512]
  float* kbuf  = hbufB + NBAT * HD;            // [32*256]
  float* betab = kbuf + NBAT * C2D;            // [32]
  float* rpart = betab + NBAT;                 // [4*32][258] (m,l,racc[256])
  float* wbuf  = rpart + 4 * NBAT * 258;       // [32][64][128] scores -> w
  float* earr  = wbuf + NBAT * TSTEPS * C1D;   // [32][64][256]
  float* varr  = earr + NBAT * TSTEPS * C2D;   // [32][64][256]

  // ---- LDS (~117 KB, 1 block/CU) ----
  __shared__ float s_tile[32 * C2D];   // c_x tile for (n,q): 32 rows x 1KB
  __shared__ float s_r[NBAT * 264];    // GRU combined r; ATTN scratch [0..1039]
  __shared__ float s_scale[192];       // [n*4+q] scales; [128+n]=M; [160+n]=invL
  __shared__ float s_wih[12 * 260];    // 4 feat x 3 gates, stride 260
  __shared__ float s_whh[12 * 516];
  __shared__ float s_wev[6 * 516];     // 2 ch x (k,e,v)
  __shared__ float s_wb[HD];

  const int n_att = bid >> 2, q_att = bid & 3;
  const int j0 = bid * 4;    // GRU features
  const int c0ch = bid * 2;  // PROJ channels

  for (int idx = tid; idx < 12 * C2D; idx += 256) {
    const int row = idx >> 8, c = idx & (C2D - 1);
    const int f = row / 3, g = row % 3;
    s_wih[row * 260 + c] = Wih[(g * HD + j0 + f) * C2D + c];
  }
  for (int idx = tid; idx < 12 * HD; idx += 256) {
    const int row = idx >> 9, c = idx & (HD - 1);
    const int f = row / 3, g = row % 3;
    s_whh[row * 516 + c] = Whh[(g * HD + j0 + f) * HD + c];
  }
  for (int idx = tid; idx < 6 * HD; idx += 256) {
    const int row = idx >> 9, c = idx & (HD - 1);
    const int ch = row / 3, which = row % 3;
    const float* __restrict__ src = (which == 0) ? Wk : (which == 1) ? We : Wv;
    s_wev[row * 516 + c] = src[(c0ch + ch) * HD + c];
  }
  for (int idx = tid; idx < HD; idx += 256) s_wb[idx] = Wb[idx];
  __syncthreads();

  unsigned gen = 0;
  // Fence-free grid barrier: all shared data goes through agent-scope atomics
  // (already at the LLC coherence point), so no L2 writeback/invalidate needed.
  auto gridbar = [&]() {
    ++gen;
    asm volatile("s_waitcnt vmcnt(0) lgkmcnt(0)" ::: "memory");
    __syncthreads();
    if (tid == 0) {
      __hip_atomic_fetch_add(bar, 1u, __ATOMIC_RELAXED, __HIP_MEMORY_SCOPE_AGENT);
      const unsigned target = gen * (unsigned)NBLK;
      while (__hip_atomic_load(bar, __ATOMIC_RELAXED, __HIP_MEMORY_SCOPE_AGENT) < target)
        __builtin_amdgcn_s_sleep(2);
    }
    __syncthreads();
  };

  // c_x prefetch: regs (issued early) -> LDS (committed late). 8 float4/thread.
  float4 pf[8];
  auto prefetch_issue = [&](int t) {
    const float* src = c_x + ((size_t)((n_att * TSTEPS + t) * C1D + q_att * 32)) * C2D + lane * 4;
#pragma unroll
    for (int k = 0; k < 8; ++k) pf[k] = *(const float4*)(src + (wid * 8 + k) * C2D);
  };
  auto prefetch_commit = [&]() {
#pragma unroll
    for (int k = 0; k < 8; ++k) *(float4*)(s_tile + (wid * 8 + k) * C2D + lane * 4) = pf[k];
  };

  // ---- PROJ: k (always), e,v (write_ev), beta (bid 0) from hsrc ----
  auto phase_proj = [&](const float* __restrict__ hsrc, int t, bool write_ev) {
    const int n = tid >> 3, s = tid & 7;
    const float* hp = hsrc + n * HD;
    float k0 = 0, e0 = 0, v0 = 0, k1 = 0, e1 = 0, v1 = 0, bp = 0;
#pragma unroll
    for (int x = 0; x < 16; ++x) {
      const int cix = s * 64 + ((4 * x + 8 * s) & 63);
      const float4 hv = aload4(hp + cix);
      k0 += dot4f(hv, *(const float4*)(s_wev + cix));
      e0 += dot4f(hv, *(const float4*)(s_wev + 516 + cix));
      v0 += dot4f(hv, *(const float4*)(s_wev + 1032 + cix));
      k1 += dot4f(hv, *(const float4*)(s_wev + 1548 + cix));
      e1 += dot4f(hv, *(const float4*)(s_wev + 2064 + cix));
      v1 += dot4f(hv, *(const float4*)(s_wev + 2580 + cix));
      if (bid == 0) bp += dot4f(hv, *(const float4*)(s_wb + cix));
    }
#pragma unroll
    for (int m = 1; m < 8; m <<= 1) {
      k0 += __shfl_xor(k0, m); e0 += __shfl_xor(e0, m); v0 += __shfl_xor(v0, m);
      k1 += __shfl_xor(k1, m); e1 += __shfl_xor(e1, m); v1 += __shfl_xor(v1, m);
    }
    if (bid == 0) {
#pragma unroll
      for (int m = 1; m < 8; m <<= 1) bp += __shfl_xor(bp, m);
    }
    if (s == 0) {
      astore2(kbuf + n * C2D + c0ch, k0 + bk[c0ch], k1 + bk[c0ch + 1]);
      if (write_ev) {
        // read only by the cscan kernel (after kernel-end flush): plain stores
        *(float2*)(earr + (size_t)(n * TSTEPS + t) * C2D + c0ch) =
            make_float2(sigm(e0 + be[c0ch]), sigm(e1 + be[c0ch + 1]));
        *(float2*)(varr + (size_t)(n * TSTEPS + t) * C2D + c0ch) =
            make_float2(v0 + bv[c0ch], v1 + bv[c0ch + 1]);
      }
      if (bid == 0) {
        const float xb = bp + bb[0];
        const float bpos = fmaxf(xb, 0.f), bneg = fminf(xb, 0.f);
        astore(betab + n, log1pf(__expf(bneg)) + bpos + log1pf(__expf(-bpos)) +
                              (1.0f - 0.6931471805599453f));
      }
    }
  };

  // ---- ATTN: online softmax over this block's 32 i-rows, from LDS tile ----
  auto phase_attn = [&](int t) {
    const float kc = aload(kbuf + n_att * C2D + tid);
    float sq = kc * kc;
#pragma unroll
    for (int m = 1; m < 64; m <<= 1) sq += __shfl_xor(sq, m);
    if (lane == 0) s_r[1036 + wid] = sq;
    __syncthreads();
    // issue next step's c_x prefetch here: flies during the dot loop below,
    // so internal-barrier vmcnt drains don't stall on it prematurely.
    if (t + 1 < TSTEPS) prefetch_issue(t + 1);
    const float kn = sqrtf(s_r[1036] + s_r[1037] + s_r[1038] + s_r[1039]);
    const float beta = aload(betab + n_att);
    const float4 kv = aload4(kbuf + n_att * C2D + lane * 4);
    float m_run = -3.0e38f, l_run = 0.f;
    float r0 = 0.f, r1 = 0.f, r2 = 0.f, r3 = 0.f;
    const int rowbase = wid * 8;
#pragma unroll
    for (int k = 0; k < 8; ++k) {
      const float4 xv = *(const float4*)(s_tile + (rowbase + k) * C2D + lane * 4);
      float np = dot4f(xv, kv);
      float cp = dot4f(xv, xv);
#pragma unroll
      for (int m = 1; m < 64; m <<= 1) {
        np += __shfl_xor(np, m);
        cp += __shfl_xor(cp, m);
      }
      const float score = beta * np / fmaxf(sqrtf(cp) * kn, 1e-8f);
      if (lane == 0) astore(wbuf + (n_att * TSTEPS + t) * C1D + q_att * 32 + rowbase + k, score);
      const float mn = fmaxf(m_run, score);
      const float corr = __expf(m_run - mn);
      const float p = __expf(score - mn);
      l_run = l_run * corr + p;
      r0 = r0 * corr + p * xv.x;
      r1 = r1 * corr + p * xv.y;
      r2 = r2 * corr + p * xv.z;
      r3 = r3 * corr + p * xv.w;
      m_run = mn;
    }
    *(float4*)(s_r + wid * 256 + lane * 4) = make_float4(r0, r1, r2, r3);
    if (lane == 0) { s_r[1024 + wid] = m_run; s_r[1028 + wid] = l_run; }
    __syncthreads();
    const float mw0 = s_r[1024], mw1 = s_r[1025], mw2 = s_r[1026], mw3 = s_r[1027];
    const float mb = fmaxf(fmaxf(mw0, mw1), fmaxf(mw2, mw3));
    const float e0 = __expf(mw0 - mb), e1 = __expf(mw1 - mb);
    const float e2 = __expf(mw2 - mb), e3 = __expf(mw3 - mb);
    const float lb = s_r[1028] * e0 + s_r[1029] * e1 + s_r[1030] * e2 + s_r[1031] * e3;
    const float racc = s_r[tid] * e0 + s_r[256 + tid] * e1 + s_r[512 + tid] * e2 + s_r[768 + tid] * e3;
    float* rp = rpart + (q_att * NBAT + n_att) * 258;
    if (tid == 0) astore2(rp, mb, lb);
    astore(rp + 2 + tid, racc);
  };

  // ---- GRU: combine r, finalize w row (bid<32), compute 4 h-features x 32 n ----
  auto phase_gru = [&](const float* __restrict__ hsrc, float* __restrict__ hnext, int t) {
    if (tid < NBAT) {
      const int n = tid;
      float mq[4], lq[4];
#pragma unroll
      for (int q = 0; q < 4; ++q) {
        const float2 ml = aload2(rpart + (q * NBAT + n) * 258);
        mq[q] = ml.x; lq[q] = ml.y;
      }
      const float M = fmaxf(fmaxf(mq[0], mq[1]), fmaxf(mq[2], mq[3]));
      float x[4], L = 0.f;
#pragma unroll
      for (int q = 0; q < 4; ++q) { x[q] = __expf(mq[q] - M); L += lq[q] * x[q]; }
      const float invL = 1.f / L;
#pragma unroll
      for (int q = 0; q < 4; ++q) s_scale[n * 4 + q] = x[q] * invL;
      s_scale[128 + n] = M;
      s_scale[160 + n] = invL;
    }
    __syncthreads();
    {
      const int c = tid;
#pragma unroll 4
      for (int n2 = 0; n2 < NBAT; ++n2) {
        float acc = 0.f;
#pragma unroll
        for (int q = 0; q < 4; ++q)
          acc += aload(rpart + (q * NBAT + n2) * 258 + 2 + c) * s_scale[n2 * 4 + q];
        s_r[n2 * 264 + c] = acc;
      }
    }
    __syncthreads();
    if (bid < NBAT && tid < C1D) {
      const float M = s_scale[128 + bid], invL = s_scale[160 + bid];
      float* wp = wbuf + (bid * TSTEPS + t) * C1D + tid;
      const float sc = aload(wp);
      *wp = __expf(sc - M) * invL;  // read only by cscan kernel: plain store
    }
    const int n = tid >> 3, s = tid & 7;
    float aR[4] = {0, 0, 0, 0}, aZ[4] = {0, 0, 0, 0};
    float aNi[4] = {0, 0, 0, 0}, aNh[4] = {0, 0, 0, 0};
    const float* rb = s_r + n * 264 + s * 32;
#pragma unroll
    for (int x = 0; x < 8; ++x) {
      const int o = (4 * x + 4 * s) & 31;
      const float4 rv = *(const float4*)(rb + o);
      const int cix = s * 32 + o;
#pragma unroll
      for (int f = 0; f < 4; ++f) {
        aR[f]  += dot4f(rv, *(const float4*)(s_wih + (f * 3 + 0) * 260 + cix));
        aZ[f]  += dot4f(rv, *(const float4*)(s_wih + (f * 3 + 1) * 260 + cix));
        aNi[f] += dot4f(rv, *(const float4*)(s_wih + (f * 3 + 2) * 260 + cix));
      }
    }
    const float* hb = hsrc + n * HD + s * 64;
#pragma unroll
    for (int x = 0; x < 16; ++x) {
      const int o = (4 * x + 8 * s) & 63;
      const float4 hv = aload4(hb + o);
      const int cix = s * 64 + o;
#pragma unroll
      for (int f = 0; f < 4; ++f) {
        aR[f]  += dot4f(hv, *(const float4*)(s_whh + (f * 3 + 0) * 516 + cix));
        aZ[f]  += dot4f(hv, *(const float4*)(s_whh + (f * 3 + 1) * 516 + cix));
        aNh[f] += dot4f(hv, *(const float4*)(s_whh + (f * 3 + 2) * 516 + cix));
      }
    }
#pragma unroll
    for (int m = 1; m < 8; m <<= 1) {
#pragma unroll
      for (int f = 0; f < 4; ++f) {
        aR[f] += __shfl_xor(aR[f], m);
        aZ[f] += __shfl_xor(aZ[f], m);
        aNi[f] += __shfl_xor(aNi[f], m);
        aNh[f] += __shfl_xor(aNh[f], m);
      }
    }
    if (s == 0) {
      const float4 hp4 = aload4(hsrc + n * HD + j0);
      const float hpv[4] = {hp4.x, hp4.y, hp4.z, hp4.w};
      float hn[4];
#pragma unroll
      for (int f = 0; f < 4; ++f) {
        const int j = j0 + f;
        const float rg = sigm(aR[f] + bih[j] + bhh[j]);
        const float z = sigm(aZ[f] + bih[HD + j] + bhh[HD + j]);
        const float ng = tanhf(aNi[f] + bih[2 * HD + j] + rg * (aNh[f] + bhh[2 * HD + j]));
        hn[f] = (1.f - z) * ng + z * hpv[f];
      }
      astore2(hnext + n * HD + j0, hn[0], hn[1]);
      astore2(hnext + n * HD + j0 + 2, hn[2], hn[3]);
      *(float4*)(hs_out + (size_t)(n * TSTEPS + t) * HD + j0) =
          make_float4(hn[0], hn[1], hn[2], hn[3]);  // host-read only: plain
    }
  };

  // ================= main =================
  prefetch_issue(0);
  phase_proj(h0, 0, false);
  prefetch_commit();
  gridbar();
  for (int t = 0; t < TSTEPS; ++t) {
    phase_attn(t);  // also issues prefetch(t+1) internally
    gridbar();
    const float* hsrc = (t == 0) ? h0 : ((t & 1) ? hbufB : hbufA);
    float* hnext = (t & 1) ? hbufA : hbufB;
    phase_gru(hsrc, hnext, t);
    gridbar();
    phase_proj(hnext, t, true);
    if (t < TSTEPS - 1) prefetch_commit();
    gridbar();
  }
}

// ---- parallel c-scan: c_t = c_{t-1}*(1 - w_t e_t) + w_t v_t, all t in registers ----
__global__ void __launch_bounds__(256) ntm_cscan(
    const float* __restrict__ c0, const float* __restrict__ wsf,
    float* __restrict__ out)
{
  const float* wbuf = wsf + 2 * NBAT * HD + NBAT * C2D + NBAT + 4 * NBAT * 258;
  const float* earr = wbuf + NBAT * TSTEPS * C1D;
  const float* varr = earr + NBAT * TSTEPS * C2D;
  float* cs_out = out + NBAT * TSTEPS * HD;

  const int tid = threadIdx.x;
  const int lane = tid & 63, wid = tid >> 6;
  const int n = blockIdx.x >> 3, g = blockIdx.x & 7;
  const int i0 = g * 16 + wid * 4;

  f32x4 c[4];
#pragma unroll
  for (int r = 0; r < 4; ++r)
    c[r] = *(const f32x4*)(c0 + ((size_t)(n * C1D + i0 + r)) * C2D + lane * 4);

  const float* ep = earr + (size_t)n * TSTEPS * C2D + lane * 4;
  const float* vp = varr + (size_t)n * TSTEPS * C2D + lane * 4;
  const float* wp = wbuf + (size_t)n * TSTEPS * C1D + i0;

  f32x4 e_nxt = *(const f32x4*)(ep);
  f32x4 v_nxt = *(const f32x4*)(vp);
  for (int t = 0; t < TSTEPS; ++t) {
    const f32x4 e4 = e_nxt, v4 = v_nxt;
    if (t + 1 < TSTEPS) {
      e_nxt = *(const f32x4*)(ep + (t + 1) * C2D);
      v_nxt = *(const f32x4*)(vp + (t + 1) * C2D);
    }
#pragma unroll
    for (int r = 0; r < 4; ++r) {
      const float wr = wp[t * C1D + r];
      c[r] = c[r] * (1.f - wr * e4) + wr * v4;
      __builtin_nontemporal_store(
          c[r], (f32x4*)(cs_out + ((size_t)((n * TSTEPS + t) * C1D + i0 + r)) * C2D + lane * 4));
    }
  }
}

extern "C" void kernel_launch(void* const* d_in, const int* in_sizes, int n_in,
                              void* d_out, int out_size, void* d_ws, size_t ws_size,
                              hipStream_t stream) {
  const float* h0 = (const float*)d_in[0];
  const float* c0 = (const float*)d_in[1];
  const float* c_x = (const float*)d_in[2];
  const float* Wk = (const float*)d_in[3];
  const float* bk = (const float*)d_in[4];
  const float* Wb = (const float*)d_in[5];
  const float* bb = (const float*)d_in[6];
  const float* We = (const float*)d_in[7];
  const float* be = (const float*)d_in[8];
  const float* Wv = (const float*)d_in[9];
  const float* bv = (const float*)d_in[10];
  const float* Wih = (const float*)d_in[11];
  const float* bih = (const float*)d_in[12];
  const float* Whh = (const float*)d_in[13];
  const float* bhh = (const float*)d_in[14];

  unsigned* bar = (unsigned*)d_ws;
  float* wsf = (float*)((char*)d_ws + 256);

  (void)hipMemsetAsync(d_ws, 0, 256, stream);  // reset barrier counter (deterministic replay)
  ntm_chain<<<dim3(NBLK), dim3(256), 0, stream>>>(h0, c_x, Wk, bk, Wb, bb, We, be, Wv, bv,
                                                  Wih, bih, Whh, bhh, (float*)d_out, wsf, bar);
  ntm_cscan<<<dim3(256), dim3(256), 0, stream>>>(c0, wsf, (float*)d_out);
}

// Round 5
// 3037.122 us; speedup vs baseline: 1.1430x; 1.1430x over previous
//
#include <hip/hip_runtime.h>
#include <math.h>

// NTM: (1) serial h-chain kernel (128 blocks, 3 grid barriers/step).
//     Barrier = per-block arrive flags on distinct cache lines (parallel relaxed
//     agent stores), master block polls all flags with 128 threads, release flag
//     broadcast. No atomic RMW contention, no L2 writeback/invalidate fences.
//     All cross-block data via agent-scope relaxed atomics (LLC-coherent).
// (2) parallel c-scan kernel streaming the 268 MB cs output.
// Shapes: N=32, T=64, C1=128, C2=256, H=512 (all f32).

#define NBAT 32
#define TSTEPS 64
#define C1D 128
#define C2D 256
#define HD 512
#define NBLK 128  // chain blocks

typedef float f32x4 __attribute__((ext_vector_type(4)));

static __device__ __forceinline__ float dot4f(float4 a, float4 b) {
  return a.x * b.x + a.y * b.y + a.z * b.z + a.w * b.w;
}
static __device__ __forceinline__ float sigm(float x) { return 1.0f / (1.0f + __expf(-x)); }

// ---- agent-scope (LLC-coherent, fence-free) access helpers ----
static __device__ __forceinline__ float aload(const float* p) {
  return __hip_atomic_load(p, __ATOMIC_RELAXED, __HIP_MEMORY_SCOPE_AGENT);
}
static __device__ __forceinline__ void astore(float* p, float v) {
  __hip_atomic_store(p, v, __ATOMIC_RELAXED, __HIP_MEMORY_SCOPE_AGENT);
}
static __device__ __forceinline__ float2 aload2(const float* p) {
  unsigned long long u = __hip_atomic_load((const unsigned long long*)p,
                                           __ATOMIC_RELAXED, __HIP_MEMORY_SCOPE_AGENT);
  union { unsigned long long u; float2 f; } c;
  c.u = u;
  return c.f;
}
static __device__ __forceinline__ void astore2(float* p, float a, float b) {
  union { float f[2]; unsigned long long u; } c;
  c.f[0] = a; c.f[1] = b;
  __hip_atomic_store((unsigned long long*)p, c.u, __ATOMIC_RELAXED, __HIP_MEMORY_SCOPE_AGENT);
}
static __device__ __forceinline__ float4 aload4(const float* p) {
  const float2 lo = aload2(p), hi = aload2(p + 2);
  return make_float4(lo.x, lo.y, hi.x, hi.y);
}

__global__ void __launch_bounds__(256) ntm_chain(
    const float* __restrict__ h0, const float* __restrict__ c_x,
    const float* __restrict__ Wk, const float* __restrict__ bk,
    const float* __restrict__ Wb, const float* __restrict__ bb,
    const float* __restrict__ We, const float* __restrict__ be,
    const float* __restrict__ Wv, const float* __restrict__ bv,
    const float* __restrict__ Wih, const float* __restrict__ bih,
    const float* __restrict__ Whh, const float* __restrict__ bhh,
    float* __restrict__ hs_out, float* __restrict__ wsf, unsigned* __restrict__ bar)
{
  const int tid = threadIdx.x;
  const int bid = blockIdx.x;
  const int lane = tid & 63;
  const int wid = tid >> 6;

  // ---- barrier area (reset to 0 each launch): flags[128] @ stride 32 uints, release @ +4096 uints
  unsigned* flags = bar;
  unsigned* release = bar + 4096;

  // ---- workspace layout (floats) ----
  float* hbufA = wsf;                          // [32*512]
  float* hbufB = hbufA + NBAT * HD;            // [32*512]
  float* kbuf  = hbufB + NBAT * HD;            // [32*256]
  float* betab = kbuf + NBAT * C2D;            // [32]
  float* rpart = betab + NBAT;                 // [4*32][258] (m,l,racc[256])
  float* wbuf  = rpart + 4 * NBAT * 258;       // [32][64][128] scores -> w
  float* earr  = wbuf + NBAT * TSTEPS * C1D;   // [32][64][256]
  float* varr  = earr + NBAT * TSTEPS * C2D;   // [32][64][256]

  // ---- LDS (~117 KB, 1 block/CU) ----
  __shared__ float s_tile[32 * C2D];   // c_x tile for (n,q): 32 rows x 1KB
  __shared__ float s_r[NBAT * 264];    // GRU combined r; ATTN scratch [0..1039]
  __shared__ float s_scale[192];       // [n*4+q] scales; [128+n]=M; [160+n]=invL
  __shared__ float s_wih[12 * 260];    // 4 feat x 3 gates, stride 260
  __shared__ float s_whh[12 * 516];
  __shared__ float s_wev[6 * 516];     // 2 ch x (k,e,v)
  __shared__ float s_wb[HD];

  const int n_att = bid >> 2, q_att = bid & 3;
  const int j0 = bid * 4;    // GRU features
  const int c0ch = bid * 2;  // PROJ channels

  for (int idx = tid; idx < 12 * C2D; idx += 256) {
    const int row = idx >> 8, c = idx & (C2D - 1);
    const int f = row / 3, g = row % 3;
    s_wih[row * 260 + c] = Wih[(g * HD + j0 + f) * C2D + c];
  }
  for (int idx = tid; idx < 12 * HD; idx += 256) {
    const int row = idx >> 9, c = idx & (HD - 1);
    const int f = row / 3, g = row % 3;
    s_whh[row * 516 + c] = Whh[(g * HD + j0 + f) * HD + c];
  }
  for (int idx = tid; idx < 6 * HD; idx += 256) {
    const int row = idx >> 9, c = idx & (HD - 1);
    const int ch = row / 3, which = row % 3;
    const float* __restrict__ src = (which == 0) ? Wk : (which == 1) ? We : Wv;
    s_wev[row * 516 + c] = src[(c0ch + ch) * HD + c];
  }
  for (int idx = tid; idx < HD; idx += 256) s_wb[idx] = Wb[idx];
  __syncthreads();

  unsigned gen = 0;
  // Contention-free grid barrier:
  //  arrive: one relaxed agent store per block to its OWN 128B line (parallel).
  //  master (bid 0): 128 threads each poll one flag (distinct lines, pipelined),
  //  then one release store. others: poll release.
  auto gridbar = [&]() {
    ++gen;
    asm volatile("s_waitcnt vmcnt(0) lgkmcnt(0)" ::: "memory");
    __syncthreads();
    if (tid == 0)
      __hip_atomic_store(flags + bid * 32, gen, __ATOMIC_RELAXED, __HIP_MEMORY_SCOPE_AGENT);
    if (bid == 0) {
      if (tid < NBLK) {
        while (__hip_atomic_load(flags + tid * 32, __ATOMIC_RELAXED,
                                 __HIP_MEMORY_SCOPE_AGENT) < gen)
          __builtin_amdgcn_s_sleep(1);
      }
      __syncthreads();
      if (tid == 0)
        __hip_atomic_store(release, gen, __ATOMIC_RELAXED, __HIP_MEMORY_SCOPE_AGENT);
    } else {
      if (tid == 0) {
        while (__hip_atomic_load(release, __ATOMIC_RELAXED, __HIP_MEMORY_SCOPE_AGENT) < gen)
          __builtin_amdgcn_s_sleep(2);
      }
    }
    __syncthreads();
  };

  // c_x prefetch: regs (issued early) -> LDS (committed late). 8 float4/thread.
  float4 pf[8];
  auto prefetch_issue = [&](int t) {
    const float* src = c_x + ((size_t)((n_att * TSTEPS + t) * C1D + q_att * 32)) * C2D + lane * 4;
#pragma unroll
    for (int k = 0; k < 8; ++k) pf[k] = *(const float4*)(src + (wid * 8 + k) * C2D);
  };
  auto prefetch_commit = [&]() {
#pragma unroll
    for (int k = 0; k < 8; ++k) *(float4*)(s_tile + (wid * 8 + k) * C2D + lane * 4) = pf[k];
  };

  // ---- PROJ: k (always), e,v (write_ev), beta (bid 0) from hsrc ----
  auto phase_proj = [&](const float* __restrict__ hsrc, int t, bool write_ev) {
    const int n = tid >> 3, s = tid & 7;
    const float* hp = hsrc + n * HD;
    float k0 = 0, e0 = 0, v0 = 0, k1 = 0, e1 = 0, v1 = 0, bp = 0;
#pragma unroll
    for (int x = 0; x < 16; ++x) {
      const int cix = s * 64 + ((4 * x + 8 * s) & 63);
      const float4 hv = aload4(hp + cix);
      k0 += dot4f(hv, *(const float4*)(s_wev + cix));
      e0 += dot4f(hv, *(const float4*)(s_wev + 516 + cix));
      v0 += dot4f(hv, *(const float4*)(s_wev + 1032 + cix));
      k1 += dot4f(hv, *(const float4*)(s_wev + 1548 + cix));
      e1 += dot4f(hv, *(const float4*)(s_wev + 2064 + cix));
      v1 += dot4f(hv, *(const float4*)(s_wev + 2580 + cix));
      if (bid == 0) bp += dot4f(hv, *(const float4*)(s_wb + cix));
    }
#pragma unroll
    for (int m = 1; m < 8; m <<= 1) {
      k0 += __shfl_xor(k0, m); e0 += __shfl_xor(e0, m); v0 += __shfl_xor(v0, m);
      k1 += __shfl_xor(k1, m); e1 += __shfl_xor(e1, m); v1 += __shfl_xor(v1, m);
    }
    if (bid == 0) {
#pragma unroll
      for (int m = 1; m < 8; m <<= 1) bp += __shfl_xor(bp, m);
    }
    if (s == 0) {
      astore2(kbuf + n * C2D + c0ch, k0 + bk[c0ch], k1 + bk[c0ch + 1]);
      if (write_ev) {
        // read only by the cscan kernel (after kernel-end flush): plain stores
        *(float2*)(earr + (size_t)(n * TSTEPS + t) * C2D + c0ch) =
            make_float2(sigm(e0 + be[c0ch]), sigm(e1 + be[c0ch + 1]));
        *(float2*)(varr + (size_t)(n * TSTEPS + t) * C2D + c0ch) =
            make_float2(v0 + bv[c0ch], v1 + bv[c0ch + 1]);
      }
      if (bid == 0) {
        const float xb = bp + bb[0];
        const float bpos = fmaxf(xb, 0.f), bneg = fminf(xb, 0.f);
        astore(betab + n, log1pf(__expf(bneg)) + bpos + log1pf(__expf(-bpos)) +
                              (1.0f - 0.6931471805599453f));
      }
    }
  };

  // ---- ATTN: online softmax over this block's 32 i-rows, from LDS tile ----
  auto phase_attn = [&](int t) {
    const float kc = aload(kbuf + n_att * C2D + tid);
    float sq = kc * kc;
#pragma unroll
    for (int m = 1; m < 64; m <<= 1) sq += __shfl_xor(sq, m);
    if (lane == 0) s_r[1036 + wid] = sq;
    __syncthreads();
    // issue next step's c_x prefetch here: flies during the dot loops below.
    if (t + 1 < TSTEPS) prefetch_issue(t + 1);
    const float kn = sqrtf(s_r[1036] + s_r[1037] + s_r[1038] + s_r[1039]);
    const float beta = aload(betab + n_att);
    const float4 kv = aload4(kbuf + n_att * C2D + lane * 4);
    const int rowbase = wid * 8;
    // batched dots + batched butterfly reductions (independent chains pipeline)
    float np[8], cp[8];
#pragma unroll
    for (int k = 0; k < 8; ++k) {
      const float4 xv = *(const float4*)(s_tile + (rowbase + k) * C2D + lane * 4);
      np[k] = dot4f(xv, kv);
      cp[k] = dot4f(xv, xv);
    }
#pragma unroll
    for (int m = 1; m < 64; m <<= 1) {
#pragma unroll
      for (int k = 0; k < 8; ++k) {
        np[k] += __shfl_xor(np[k], m);
        cp[k] += __shfl_xor(cp[k], m);
      }
    }
    float m_run = -3.0e38f, l_run = 0.f;
    float r0 = 0.f, r1 = 0.f, r2 = 0.f, r3 = 0.f;
#pragma unroll
    for (int k = 0; k < 8; ++k) {
      const float4 xv = *(const float4*)(s_tile + (rowbase + k) * C2D + lane * 4);
      const float score = beta * np[k] / fmaxf(sqrtf(cp[k]) * kn, 1e-8f);
      if (lane == 0) astore(wbuf + (n_att * TSTEPS + t) * C1D + q_att * 32 + rowbase + k, score);
      const float mn = fmaxf(m_run, score);
      const float corr = __expf(m_run - mn);
      const float p = __expf(score - mn);
      l_run = l_run * corr + p;
      r0 = r0 * corr + p * xv.x;
      r1 = r1 * corr + p * xv.y;
      r2 = r2 * corr + p * xv.z;
      r3 = r3 * corr + p * xv.w;
      m_run = mn;
    }
    *(float4*)(s_r + wid * 256 + lane * 4) = make_float4(r0, r1, r2, r3);
    if (lane == 0) { s_r[1024 + wid] = m_run; s_r[1028 + wid] = l_run; }
    __syncthreads();
    const float mw0 = s_r[1024], mw1 = s_r[1025], mw2 = s_r[1026], mw3 = s_r[1027];
    const float mb = fmaxf(fmaxf(mw0, mw1), fmaxf(mw2, mw3));
    const float e0 = __expf(mw0 - mb), e1 = __expf(mw1 - mb);
    const float e2 = __expf(mw2 - mb), e3 = __expf(mw3 - mb);
    const float lb = s_r[1028] * e0 + s_r[1029] * e1 + s_r[1030] * e2 + s_r[1031] * e3;
    const float racc = s_r[tid] * e0 + s_r[256 + tid] * e1 + s_r[512 + tid] * e2 + s_r[768 + tid] * e3;
    float* rp = rpart + (q_att * NBAT + n_att) * 258;
    if (tid == 0) astore2(rp, mb, lb);
    astore(rp + 2 + tid, racc);
  };

  // ---- GRU: combine r, finalize w row (bid<32), compute 4 h-features x 32 n ----
  auto phase_gru = [&](const float* __restrict__ hsrc, float* __restrict__ hnext, int t) {
    if (tid < NBAT) {
      const int n = tid;
      float mq[4], lq[4];
#pragma unroll
      for (int q = 0; q < 4; ++q) {
        const float2 ml = aload2(rpart + (q * NBAT + n) * 258);
        mq[q] = ml.x; lq[q] = ml.y;
      }
      const float M = fmaxf(fmaxf(mq[0], mq[1]), fmaxf(mq[2], mq[3]));
      float x[4], L = 0.f;
#pragma unroll
      for (int q = 0; q < 4; ++q) { x[q] = __expf(mq[q] - M); L += lq[q] * x[q]; }
      const float invL = 1.f / L;
#pragma unroll
      for (int q = 0; q < 4; ++q) s_scale[n * 4 + q] = x[q] * invL;
      s_scale[128 + n] = M;
      s_scale[160 + n] = invL;
    }
    __syncthreads();
    {
      const int c = tid;
#pragma unroll 4
      for (int n2 = 0; n2 < NBAT; ++n2) {
        float acc = 0.f;
#pragma unroll
        for (int q = 0; q < 4; ++q)
          acc += aload(rpart + (q * NBAT + n2) * 258 + 2 + c) * s_scale[n2 * 4 + q];
        s_r[n2 * 264 + c] = acc;
      }
    }
    __syncthreads();
    if (bid < NBAT && tid < C1D) {
      const float M = s_scale[128 + bid], invL = s_scale[160 + bid];
      float* wp = wbuf + (bid * TSTEPS + t) * C1D + tid;
      const float sc = aload(wp);
      *wp = __expf(sc - M) * invL;  // read only by cscan kernel: plain store
    }
    const int n = tid >> 3, s = tid & 7;
    float aR[4] = {0, 0, 0, 0}, aZ[4] = {0, 0, 0, 0};
    float aNi[4] = {0, 0, 0, 0}, aNh[4] = {0, 0, 0, 0};
    const float* rb = s_r + n * 264 + s * 32;
#pragma unroll
    for (int x = 0; x < 8; ++x) {
      const int o = (4 * x + 4 * s) & 31;
      const float4 rv = *(const float4*)(rb + o);
      const int cix = s * 32 + o;
#pragma unroll
      for (int f = 0; f < 4; ++f) {
        aR[f]  += dot4f(rv, *(const float4*)(s_wih + (f * 3 + 0) * 260 + cix));
        aZ[f]  += dot4f(rv, *(const float4*)(s_wih + (f * 3 + 1) * 260 + cix));
        aNi[f] += dot4f(rv, *(const float4*)(s_wih + (f * 3 + 2) * 260 + cix));
      }
    }
    const float* hb = hsrc + n * HD + s * 64;
#pragma unroll
    for (int x = 0; x < 16; ++x) {
      const int o = (4 * x + 8 * s) & 63;
      const float4 hv = aload4(hb + o);
      const int cix = s * 64 + o;
#pragma unroll
      for (int f = 0; f < 4; ++f) {
        aR[f]  += dot4f(hv, *(const float4*)(s_whh + (f * 3 + 0) * 516 + cix));
        aZ[f]  += dot4f(hv, *(const float4*)(s_whh + (f * 3 + 1) * 516 + cix));
        aNh[f] += dot4f(hv, *(const float4*)(s_whh + (f * 3 + 2) * 516 + cix));
      }
    }
#pragma unroll
    for (int m = 1; m < 8; m <<= 1) {
#pragma unroll
      for (int f = 0; f < 4; ++f) {
        aR[f] += __shfl_xor(aR[f], m);
        aZ[f] += __shfl_xor(aZ[f], m);
        aNi[f] += __shfl_xor(aNi[f], m);
        aNh[f] += __shfl_xor(aNh[f], m);
      }
    }
    if (s == 0) {
      const float4 hp4 = aload4(hsrc + n * HD + j0);
      const float hpv[4] = {hp4.x, hp4.y, hp4.z, hp4.w};
      float hn[4];
#pragma unroll
      for (int f = 0; f < 4; ++f) {
        const int j = j0 + f;
        const float rg = sigm(aR[f] + bih[j] + bhh[j]);
        const float z = sigm(aZ[f] + bih[HD + j] + bhh[HD + j]);
        const float ng = tanhf(aNi[f] + bih[2 * HD + j] + rg * (aNh[f] + bhh[2 * HD + j]));
        hn[f] = (1.f - z) * ng + z * hpv[f];
      }
      astore2(hnext + n * HD + j0, hn[0], hn[1]);
      astore2(hnext + n * HD + j0 + 2, hn[2], hn[3]);
      *(float4*)(hs_out + (size_t)(n * TSTEPS + t) * HD + j0) =
          make_float4(hn[0], hn[1], hn[2], hn[3]);  // host-read only: plain
    }
  };

  // ================= main =================
  prefetch_issue(0);
  phase_proj(h0, 0, false);
  prefetch_commit();
  gridbar();
  for (int t = 0; t < TSTEPS; ++t) {
    phase_attn(t);  // also issues prefetch(t+1) internally
    gridbar();
    const float* hsrc = (t == 0) ? h0 : ((t & 1) ? hbufB : hbufA);
    float* hnext = (t & 1) ? hbufA : hbufB;
    phase_gru(hsrc, hnext, t);
    gridbar();
    phase_proj(hnext, t, true);
    if (t < TSTEPS - 1) prefetch_commit();
    gridbar();
  }
}

// ---- parallel c-scan: c_t = c_{t-1}*(1 - w_t e_t) + w_t v_t, all t in registers ----
__global__ void __launch_bounds__(256) ntm_cscan(
    const float* __restrict__ c0, const float* __restrict__ wsf,
    float* __restrict__ out)
{
  const float* wbuf = wsf + 2 * NBAT * HD + NBAT * C2D + NBAT + 4 * NBAT * 258;
  const float* earr = wbuf + NBAT * TSTEPS * C1D;
  const float* varr = earr + NBAT * TSTEPS * C2D;
  float* cs_out = out + NBAT * TSTEPS * HD;

  const int tid = threadIdx.x;
  const int lane = tid & 63, wid = tid >> 6;
  const int n = blockIdx.x >> 3, g = blockIdx.x & 7;
  const int i0 = g * 16 + wid * 4;

  f32x4 c[4];
#pragma unroll
  for (int r = 0; r < 4; ++r)
    c[r] = *(const f32x4*)(c0 + ((size_t)(n * C1D + i0 + r)) * C2D + lane * 4);

  const float* ep = earr + (size_t)n * TSTEPS * C2D + lane * 4;
  const float* vp = varr + (size_t)n * TSTEPS * C2D + lane * 4;
  const float* wp = wbuf + (size_t)n * TSTEPS * C1D + i0;

  f32x4 e_nxt = *(const f32x4*)(ep);
  f32x4 v_nxt = *(const f32x4*)(vp);
  for (int t = 0; t < TSTEPS; ++t) {
    const f32x4 e4 = e_nxt, v4 = v_nxt;
    if (t + 1 < TSTEPS) {
      e_nxt = *(const f32x4*)(ep + (t + 1) * C2D);
      v_nxt = *(const f32x4*)(vp + (t + 1) * C2D);
    }
#pragma unroll
    for (int r = 0; r < 4; ++r) {
      const float wr = wp[t * C1D + r];
      c[r] = c[r] * (1.f - wr * e4) + wr * v4;
      __builtin_nontemporal_store(
          c[r], (f32x4*)(cs_out + ((size_t)((n * TSTEPS + t) * C1D + i0 + r)) * C2D + lane * 4));
    }
  }
}

extern "C" void kernel_launch(void* const* d_in, const int* in_sizes, int n_in,
                              void* d_out, int out_size, void* d_ws, size_t ws_size,
                              hipStream_t stream) {
  const float* h0 = (const float*)d_in[0];
  const float* c0 = (const float*)d_in[1];
  const float* c_x = (const float*)d_in[2];
  const float* Wk = (const float*)d_in[3];
  const float* bk = (const float*)d_in[4];
  const float* Wb = (const float*)d_in[5];
  const float* bb = (const float*)d_in[6];
  const float* We = (const float*)d_in[7];
  const float* be = (const float*)d_in[8];
  const float* Wv = (const float*)d_in[9];
  const float* bv = (const float*)d_in[10];
  const float* Wih = (const float*)d_in[11];
  const float* bih = (const float*)d_in[12];
  const float* Whh = (const float*)d_in[13];
  const float* bhh = (const float*)d_in[14];

  unsigned* bar = (unsigned*)d_ws;
  float* wsf = (float*)((char*)d_ws + 32768);

  (void)hipMemsetAsync(d_ws, 0, 32768, stream);  // reset barrier flags (deterministic replay)
  ntm_chain<<<dim3(NBLK), dim3(256), 0, stream>>>(h0, c_x, Wk, bk, Wb, bb, We, be, Wv, bv,
                                                  Wih, bih, Whh, bhh, (float*)d_out, wsf, bar);
  ntm_cscan<<<dim3(256), dim3(256), 0, stream>>>(c0, wsf, (float*)d_out);
}